// Round 1
// baseline (450.863 us; speedup 1.0000x reference)
//
#include <hip/hip_runtime.h>

#define NB    128            // batch
#define WD    300
#define IDIM  2048
#define FEAT  (WD * IDIM)    // 614400
#define CHUNKS 16
#define VECS_TOTAL   (FEAT / 4)          // 153600 float4 per sample
#define VECS_CHUNK   (VECS_TOTAL / CHUNKS) // 9600
#define THREADS 256

// d_out is re-poisoned to 0xAA before every timed launch: initialize it with
// the bias, then the main kernel atomically accumulates partial dots.
__global__ void init_out_kernel(const float* __restrict__ align_b,
                                float* __restrict__ out) {
    int t = threadIdx.x;              // 256 threads == 128*2 outputs
    out[t] = align_b[t & 1];
}

__global__ __launch_bounds__(THREADS)
void oan_reduce_kernel(const float* __restrict__ ims,      // [NB, IDIM]
                       const int*   __restrict__ words,    // [NB]
                       const float* __restrict__ embed_w,  // [VOCAB, WD]
                       const float* __restrict__ align_w,  // [2, FEAT]
                       const float* __restrict__ drop,     // [NB, FEAT]
                       float* __restrict__ out)            // [NB, 2]
{
    __shared__ float s_ims[IDIM];     // 8 KB: this sample's image row
    __shared__ float s_wv[WD];        // 1.2 KB: this sample's embedding row
    __shared__ float s_red[8];        // 4 waves x 2 accumulators

    const int b     = blockIdx.y;
    const int chunk = blockIdx.x;
    const int tid   = threadIdx.x;

    // Stage ims row (vectorized) and embedding row into LDS.
    const float4* ims4   = (const float4*)(ims + (size_t)b * IDIM);
    float4*       s_ims4 = (float4*)s_ims;
    for (int v = tid; v < IDIM / 4; v += THREADS) s_ims4[v] = ims4[v];
    const float* wvp = embed_w + (size_t)words[b] * WD;
    for (int w = tid; w < WD; w += THREADS) s_wv[w] = wvp[w];
    __syncthreads();

    const float4* dm4 = (const float4*)(drop + (size_t)b * FEAT);
    const float4* aw0 = (const float4*)(align_w);
    const float4* aw1 = (const float4*)(align_w + FEAT);

    float acc0 = 0.f, acc1 = 0.f;
    const int v0 = chunk * VECS_CHUNK;
    for (int v = v0 + tid; v < v0 + VECS_CHUNK; v += THREADS) {
        const int k  = v << 2;                       // element index
        const float wv = s_wv[k >> 11];              // same w for all 4 elems
        const float4 im = s_ims4[(k & (IDIM - 1)) >> 2];
        const float4 d  = dm4[v];
        const float4 a0 = aw0[v];
        const float4 a1 = aw1[v];
        const float p0 = wv * im.x * d.x;
        const float p1 = wv * im.y * d.y;
        const float p2 = wv * im.z * d.z;
        const float p3 = wv * im.w * d.w;
        acc0 += p0 * a0.x + p1 * a0.y + p2 * a0.z + p3 * a0.w;
        acc1 += p0 * a1.x + p1 * a1.y + p2 * a1.z + p3 * a1.w;
    }

    // 64-lane wave reduction, then cross-wave via LDS.
    #pragma unroll
    for (int off = 32; off > 0; off >>= 1) {
        acc0 += __shfl_down(acc0, off, 64);
        acc1 += __shfl_down(acc1, off, 64);
    }
    const int lane = tid & 63;
    const int wave = tid >> 6;
    if (lane == 0) { s_red[wave * 2] = acc0; s_red[wave * 2 + 1] = acc1; }
    __syncthreads();
    if (tid == 0) {
        const float t0 = s_red[0] + s_red[2] + s_red[4] + s_red[6];
        const float t1 = s_red[1] + s_red[3] + s_red[5] + s_red[7];
        atomicAdd(&out[b * 2 + 0], t0);
        atomicAdd(&out[b * 2 + 1], t1);
    }
}

extern "C" void kernel_launch(void* const* d_in, const int* in_sizes, int n_in,
                              void* d_out, int out_size, void* d_ws, size_t ws_size,
                              hipStream_t stream) {
    const float* ims     = (const float*)d_in[0];
    const int*   words   = (const int*)  d_in[1];
    const float* embed_w = (const float*)d_in[2];
    const float* align_w = (const float*)d_in[3];
    const float* align_b = (const float*)d_in[4];
    const float* drop    = (const float*)d_in[5];
    float* out = (float*)d_out;

    init_out_kernel<<<1, 256, 0, stream>>>(align_b, out);
    dim3 grid(CHUNKS, NB);
    oan_reduce_kernel<<<grid, THREADS, 0, stream>>>(ims, words, embed_w,
                                                    align_w, drop, out);
}

// Round 6
// 424.140 us; speedup vs baseline: 1.0630x; 1.0630x over previous
//
#include <hip/hip_runtime.h>

#define NB    128            // batch
#define WD    300
#define IDIM  2048
#define FEAT  (WD * IDIM)    // 614400
#define VECS  (FEAT / 4)     // 153600 float4 per sample
#define CHUNKS 32
#define VCH   (VECS / CHUNKS) // 4800 float4 per chunk
#define THREADS 256

// Native clang vector type: __builtin_nontemporal_load accepts this
// (it rejects HIP_vector_type<float,4>*). Same 16B layout as float4.
typedef float f32x4 __attribute__((ext_vector_type(4)));

// d_out is re-poisoned to 0xAA before every timed launch: initialize it with
// the bias, then the main kernel atomically accumulates partial dots.
__global__ void init_out_kernel(const float* __restrict__ align_b,
                                float* __restrict__ out) {
    int t = threadIdx.x;              // 256 threads == 128*2 outputs
    out[t] = align_b[t & 1];
}

// Two samples per block: halves align_w L2 traffic, doubles FLOP per aw load.
// ims lives in registers: with stride-256 float4 indexing each thread only
// ever touches (v & 511) and ((v+256) & 511) -> 2 float4 per sample.
__global__ __launch_bounds__(THREADS)
void oan_reduce2_kernel(const float* __restrict__ ims,      // [NB, IDIM]
                        const int*   __restrict__ words,    // [NB]
                        const float* __restrict__ embed_w,  // [VOCAB, WD]
                        const float* __restrict__ align_w,  // [2, FEAT]
                        const float* __restrict__ drop,     // [NB, FEAT]
                        float* __restrict__ out)            // [NB, 2]
{
    __shared__ float s_wv[2][WD];     // two embedding rows
    __shared__ float s_red[16];       // 4 waves x 4 accumulators

    const int chunk = blockIdx.x;
    const int b0    = blockIdx.y * 2;
    const int b1    = b0 + 1;
    const int tid   = threadIdx.x;

    // Stage the two embedding rows into LDS.
    const float* wv0p = embed_w + (size_t)words[b0] * WD;
    const float* wv1p = embed_w + (size_t)words[b1] * WD;
    for (int w = tid; w < WD; w += THREADS) {
        s_wv[0][w] = wv0p[w];
        s_wv[1][w] = wv1p[w];
    }

    // Preload the (only) 2 ims float4 each thread will ever need, per sample.
    const f32x4* imr0 = (const f32x4*)(ims + (size_t)b0 * IDIM);
    const f32x4* imr1 = (const f32x4*)(ims + (size_t)b1 * IDIM);
    const int v0   = chunk * VCH;
    int       v    = v0 + tid;
    const int vend = v0 + VCH;
    const f32x4 imA0 = imr0[v & 511];
    const f32x4 imA1 = imr1[v & 511];
    const f32x4 imB0 = imr0[(v + 256) & 511];
    const f32x4 imB1 = imr1[(v + 256) & 511];
    __syncthreads();

    const f32x4* dm0 = (const f32x4*)(drop + (size_t)b0 * FEAT);
    const f32x4* dm1 = (const f32x4*)(drop + (size_t)b1 * FEAT);
    const f32x4* aw0 = (const f32x4*)(align_w);
    const f32x4* aw1 = (const f32x4*)(align_w + FEAT);

    float a00 = 0.f, a01 = 0.f, a10 = 0.f, a11 = 0.f; // [sample][out]

#define BODY(VV, IM0, IM1) {                                                  \
        const float  w0 = s_wv[0][(VV) >> 9];                                 \
        const float  w1 = s_wv[1][(VV) >> 9];                                 \
        const f32x4 d0 = __builtin_nontemporal_load(&dm0[VV]);                \
        const f32x4 d1 = __builtin_nontemporal_load(&dm1[VV]);                \
        const f32x4 g0 = aw0[VV];                                             \
        const f32x4 g1 = aw1[VV];                                             \
        float p0 = w0 * (IM0).x * d0.x, p1 = w0 * (IM0).y * d0.y;             \
        float p2 = w0 * (IM0).z * d0.z, p3 = w0 * (IM0).w * d0.w;             \
        a00 += p0 * g0.x + p1 * g0.y + p2 * g0.z + p3 * g0.w;                 \
        a01 += p0 * g1.x + p1 * g1.y + p2 * g1.z + p3 * g1.w;                 \
        p0 = w1 * (IM1).x * d1.x; p1 = w1 * (IM1).y * d1.y;                   \
        p2 = w1 * (IM1).z * d1.z; p3 = w1 * (IM1).w * d1.w;                   \
        a10 += p0 * g0.x + p1 * g0.y + p2 * g0.z + p3 * g0.w;                 \
        a11 += p0 * g1.x + p1 * g1.y + p2 * g1.z + p3 * g1.w;                 \
    }

    for (; v + 256 < vend; v += 512) {
        BODY(v,       imA0, imA1);
        BODY(v + 256, imB0, imB1);
    }
    if (v < vend) BODY(v, imA0, imA1);
#undef BODY

    // 64-lane wave reduction, then cross-wave via LDS.
    #pragma unroll
    for (int off = 32; off > 0; off >>= 1) {
        a00 += __shfl_down(a00, off, 64);
        a01 += __shfl_down(a01, off, 64);
        a10 += __shfl_down(a10, off, 64);
        a11 += __shfl_down(a11, off, 64);
    }
    const int lane = tid & 63;
    const int wave = tid >> 6;
    if (lane == 0) {
        s_red[wave * 4 + 0] = a00;
        s_red[wave * 4 + 1] = a01;
        s_red[wave * 4 + 2] = a10;
        s_red[wave * 4 + 3] = a11;
    }
    __syncthreads();
    if (tid < 4) {
        const float t = s_red[tid] + s_red[4 + tid] + s_red[8 + tid] + s_red[12 + tid];
        atomicAdd(&out[b0 * 2 + tid], t);   // covers b0 (tid 0,1) and b1 (tid 2,3)
    }
}

extern "C" void kernel_launch(void* const* d_in, const int* in_sizes, int n_in,
                              void* d_out, int out_size, void* d_ws, size_t ws_size,
                              hipStream_t stream) {
    const float* ims     = (const float*)d_in[0];
    const int*   words   = (const int*)  d_in[1];
    const float* embed_w = (const float*)d_in[2];
    const float* align_w = (const float*)d_in[3];
    const float* align_b = (const float*)d_in[4];
    const float* drop    = (const float*)d_in[5];
    float* out = (float*)d_out;

    init_out_kernel<<<1, 256, 0, stream>>>(align_b, out);
    dim3 grid(CHUNKS, NB / 2);
    oan_reduce2_kernel<<<grid, THREADS, 0, stream>>>(ims, words, embed_w,
                                                     align_w, drop, out);
}